// Round 5
// baseline (199.308 us; speedup 1.0000x reference)
//
#include <hip/hip_runtime.h>
#include <math.h>

#define S_LEN 2048
#define HID   1024
#define NH    16
#define HD    64
#define NM    128
#define CAUG  192
#define KC    64
#define NT    (S_LEN / KC)
#define NSPLIT 3

constexpr float ALPHA = 0.9f;

typedef __attribute__((ext_vector_type(8))) short bf16x8;
typedef __attribute__((ext_vector_type(4))) short bf16x4;
typedef __attribute__((ext_vector_type(4))) float f32x4;
typedef __attribute__((ext_vector_type(4))) int   int4v;

#define MFMA(a,b,c) __builtin_amdgcn_mfma_f32_16x16x32_bf16(a,b,c,0,0,0)

static __device__ inline short f2bf(float f) {
    unsigned u = __float_as_uint(f);
    u += 0x7fffu + ((u >> 16) & 1u);      // RNE
    return (short)(u >> 16);
}
static __device__ inline float bf2f(short s) {
    return __uint_as_float(((unsigned)(unsigned short)s) << 16);
}

// ---------------------------------------------------------------------------
// fp32 -> bf16 conversion: hs + 4 weights, float4-wide; tail range does the
// omega [h][d][m] -> om_t bf16 [h][m][d] transpose.
// ---------------------------------------------------------------------------
__global__ __launch_bounds__(256)
void conv_kernel(const float* __restrict__ hs,
                 const float* __restrict__ Wq, const float* __restrict__ Wk,
                 const float* __restrict__ Wv, const float* __restrict__ Wo,
                 const float* __restrict__ omega,
                 short* __restrict__ hsb, short* __restrict__ wqb, short* __restrict__ wkb,
                 short* __restrict__ wvb, short* __restrict__ wob, short* __restrict__ omtb)
{
    int i = blockIdx.x * 256 + threadIdx.x;           // f4-unit index
    if (i >= 1605632) return;
    if (i >= 1572864) {                               // omega transpose tail
        int j = (i - 1572864) * 4;                    // elem index in [h][d][m]
        int h = j >> 13, rem = j & 8191;
        int d = rem >> 7, m = rem & 127;
        float4 v = *(const float4*)(omega + j);       // 4 consecutive m
        short* dst = omtb + ((h * 128 + m) << 6) + d; // [h][m][d]
        dst[0]       = f2bf(v.x);
        dst[64]      = f2bf(v.y);
        dst[128]     = f2bf(v.z);
        dst[192]     = f2bf(v.w);
        return;
    }
    const float* src; short* dst; int off;
    if (i < 524288) { src = hs; dst = hsb; off = i; }
    else {
        int j = i - 524288;
        int r = j >> 18;              // 0..3
        off = j & 262143;
        src = (r == 0) ? Wq : (r == 1) ? Wk : (r == 2) ? Wv : Wo;
        dst = (r == 0) ? wqb : (r == 1) ? wkb : (r == 2) ? wvb : wob;
    }
    float4 v = ((const float4*)src)[off];
    bf16x4 o; o[0] = f2bf(v.x); o[1] = f2bf(v.y); o[2] = f2bf(v.z); o[3] = f2bf(v.w);
    ((bf16x4*)dst)[off] = o;
}

// ---------------------------------------------------------------------------
// bf16 MFMA GEMM: C = A(2048x1024) @ W(1024x1024)^T + bias
// mode 0: C bf16 [m][1024];  mode 1: C bf16 transposed [n][Mrows];  mode 2: C f32
// ---------------------------------------------------------------------------
__global__ __launch_bounds__(256)
void gemm_mfma(const short* __restrict__ A,
               const short* __restrict__ W0, const float* __restrict__ b0, void* C0,
               const short* __restrict__ W1, const float* __restrict__ b1, void* C1,
               const short* __restrict__ W2, const float* __restrict__ b2, void* C2,
               int m0_, int m1_, int m2_, int Mrows)
{
    const short* W; const float* bias; void* C; int mode;
    if (blockIdx.z == 0)      { W = W0; bias = b0; C = C0; mode = m0_; }
    else if (blockIdx.z == 1) { W = W1; bias = b1; C = C1; mode = m1_; }
    else                      { W = W2; bias = b2; C = C2; mode = m2_; }

    __shared__ short As[128][40];
    __shared__ short Bs[128][40];

    const int tid = threadIdx.x;
    const int wave = tid >> 6, lane = tid & 63;
    const int l15 = lane & 15, l4 = lane >> 4;
    const int wm = wave >> 1, wn = wave & 1;
    const int m0 = blockIdx.y * 128, n0 = blockIdx.x * 128;

    const int srow = (tid >> 2);
    const int scol = (tid & 3) * 16;

    f32x4 acc[4][4];
#pragma unroll
    for (int i = 0; i < 4; ++i)
#pragma unroll
        for (int j = 0; j < 4; ++j) acc[i][j] = (f32x4){0.f,0.f,0.f,0.f};

    int4v apre[2], bpre[2];
#pragma unroll
    for (int it = 0; it < 2; ++it) {
        apre[it] = *(const int4v*)((const char*)A + (size_t)(m0 + srow + it*64) * 2048 + scol);
        bpre[it] = *(const int4v*)((const char*)W + (size_t)(n0 + srow + it*64) * 2048 + scol);
    }

    for (int ks = 0; ks < 32; ++ks) {
        __syncthreads();
#pragma unroll
        for (int it = 0; it < 2; ++it) {
            *(int4v*)((char*)&As[0][0] + (srow + it*64) * 80 + scol) = apre[it];
            *(int4v*)((char*)&Bs[0][0] + (srow + it*64) * 80 + scol) = bpre[it];
        }
        __syncthreads();
        if (ks + 1 < 32) {
            const int kb = (ks + 1) * 64;
#pragma unroll
            for (int it = 0; it < 2; ++it) {
                apre[it] = *(const int4v*)((const char*)A + (size_t)(m0 + srow + it*64) * 2048 + kb + scol);
                bpre[it] = *(const int4v*)((const char*)W + (size_t)(n0 + srow + it*64) * 2048 + kb + scol);
            }
        }
        bf16x8 af[4], bf[4];
#pragma unroll
        for (int mi = 0; mi < 4; ++mi)
            af[mi] = *(const bf16x8*)((const char*)&As[0][0] + (wm*64 + mi*16 + l15) * 80 + l4*16);
#pragma unroll
        for (int nj = 0; nj < 4; ++nj)
            bf[nj] = *(const bf16x8*)((const char*)&Bs[0][0] + (wn*64 + nj*16 + l15) * 80 + l4*16);
#pragma unroll
        for (int mi = 0; mi < 4; ++mi)
#pragma unroll
            for (int nj = 0; nj < 4; ++nj)
                acc[mi][nj] = MFMA(af[mi], bf[nj], acc[mi][nj]);
    }

#pragma unroll
    for (int nj = 0; nj < 4; ++nj) {
        const int nglob = n0 + wn*64 + nj*16 + l15;
        const float bn = bias[nglob];
#pragma unroll
        for (int mi = 0; mi < 4; ++mi) {
            const int mbase = m0 + wm*64 + mi*16 + l4*4;
            if (mode == 0) {
#pragma unroll
                for (int r = 0; r < 4; ++r)
                    ((short*)C)[(size_t)(mbase + r) * 1024 + nglob] = f2bf(acc[mi][nj][r] + bn);
            } else if (mode == 1) {
                bf16x4 pk;
#pragma unroll
                for (int r = 0; r < 4; ++r) pk[r] = f2bf(acc[mi][nj][r] + bn);
                *(bf16x4*)((short*)C + (size_t)nglob * Mrows + mbase) = pk;
            } else {
#pragma unroll
                for (int r = 0; r < 4; ++r)
                    ((float*)C)[(size_t)(mbase + r) * 1024 + nglob] = acc[mi][nj][r] + bn;
            }
        }
    }
}

// ---------------------------------------------------------------------------
// phi2 (MFMA): per block = one (src, head, 64 s-rows)
// ---------------------------------------------------------------------------
__global__ __launch_bounds__(256)
void phi2_kernel(const short* __restrict__ qbuf, const short* __restrict__ kbuf,
                 const short* __restrict__ omtb, const float* __restrict__ rffb,
                 short* __restrict__ Qa, short* __restrict__ Ka)
{
    __shared__ short om[128][72];
    __shared__ float bsh[128];

    const int src = blockIdx.z, h = blockIdx.y;
    const int s0 = blockIdx.x * 64;
    const short* X = src ? kbuf : qbuf;
    short* Out     = src ? Ka : Qa;
    const float fq   = src ? 1.0f : (ALPHA * 0.125f);
    const float fphi = src ? 1.0f : ((1.0f - ALPHA) * 0.125f);

    const int tid = threadIdx.x, wave = tid >> 6, lane = tid & 63;
    const int l15 = lane & 15, l4 = lane >> 4;

    {
        const char* gsrc = (const char*)(omtb + ((size_t)h << 13));
#pragma unroll
        for (int it = 0; it < 4; ++it) {
            int f = tid * 16 + it * 4096;
            int row = f >> 7, colb = f & 127;
            *(int4v*)((char*)&om[0][0] + row * 144 + colb) = *(const int4v*)(gsrc + f);
        }
        if (tid < 128) bsh[tid] = rffb[h * 128 + tid];
    }
    __syncthreads();

    const int srow = s0 + wave * 16 + l15;

    bf16x8 xf[2];
#pragma unroll
    for (int cs = 0; cs < 2; ++cs)
        xf[cs] = *(const bf16x8*)(X + (size_t)srow * HID + h * HD + cs * 32 + l4 * 8);

    float ss = 0.f;
#pragma unroll
    for (int cs = 0; cs < 2; ++cs)
#pragma unroll
        for (int j = 0; j < 8; ++j) { float v = bf2f(xf[cs][j]); ss = fmaf(v, v, ss); }
    ss += __shfl_xor(ss, 16);
    ss += __shfl_xor(ss, 32);
    const float inv = 1.0f / (sqrtf(ss) + 1e-6f);

    bf16x8 qn[2];
#pragma unroll
    for (int cs = 0; cs < 2; ++cs) {
        bf16x8 o, w;
#pragma unroll
        for (int j = 0; j < 8; ++j) {
            float v = bf2f(xf[cs][j]);
            o[j] = f2bf(v * inv);
            w[j] = f2bf(v * fq);
        }
        qn[cs] = o;
        *(bf16x8*)(Out + ((size_t)h * S_LEN + srow) * CAUG + cs * 32 + l4 * 8) = w;
    }

    f32x4 pacc[8];
#pragma unroll
    for (int t = 0; t < 8; ++t) pacc[t] = (f32x4){0.f,0.f,0.f,0.f};
#pragma unroll
    for (int t = 0; t < 8; ++t)
#pragma unroll
        for (int cs = 0; cs < 2; ++cs) {
            bf16x8 bf = *(const bf16x8*)((const char*)&om[0][0] + (t*16 + l15) * 144 + cs*64 + l4*16);
            pacc[t] = MFMA(qn[cs], bf, pacc[t]);
        }

    float ph[8][4];
    float ps[4] = {0.f, 0.f, 0.f, 0.f};
#pragma unroll
    for (int t = 0; t < 8; ++t) {
        const float bv = bsh[t * 16 + l15];
#pragma unroll
        for (int r = 0; r < 4; ++r) {
            float p = pacc[t][r] + bv;
            float c = 0.125f * __cosf(p);
            ph[t][r] = c;
            ps[r] = fmaf(c, c, ps[r]);
        }
    }
#pragma unroll
    for (int r = 0; r < 4; ++r) {
        ps[r] += __shfl_xor(ps[r], 1);
        ps[r] += __shfl_xor(ps[r], 2);
        ps[r] += __shfl_xor(ps[r], 4);
        ps[r] += __shfl_xor(ps[r], 8);
    }
    float inv2[4];
#pragma unroll
    for (int r = 0; r < 4; ++r) inv2[r] = fphi / (sqrtf(ps[r]) + 1e-6f);

#pragma unroll
    for (int t = 0; t < 8; ++t)
#pragma unroll
        for (int r = 0; r < 4; ++r)
            Out[((size_t)h * S_LEN + s0 + wave * 16 + l4 * 4 + r) * CAUG + 64 + t * 16 + l15]
                = f2bf(ph[t][r] * inv2[r]);
}

// ---------------------------------------------------------------------------
// MFMA flash attention with split-K.  qj=2 (32 q/wave), 4 waves -> 128 q/block.
// Grid (16 qtiles, 16 heads, 3 ksplits) = 768 blocks = 3 blocks/CU.
// Each block: independent online softmax over its chunk range; writes f32
// partials O^T, (m, l).  No final division (merge kernel does it).
// ---------------------------------------------------------------------------
__global__ __launch_bounds__(256, 3)
void flash_mfma(const short* __restrict__ Qa, const short* __restrict__ Ka,
                const short* __restrict__ vt, const float* __restrict__ mask,
                float* __restrict__ Opart, float* __restrict__ mlpart)
{
    __shared__ short Ks[64][200];      // 192 + 8 pad
    __shared__ short Vt[64][72];       // 64 + 8 pad
    __shared__ short Pl[4][32][72];    // per-wave private P (32 q rows)

    const int tid = threadIdx.x;
    const int wave = tid >> 6, lane = tid & 63;
    const int l15 = lane & 15, l4 = lane >> 4;
    const int h = blockIdx.y;
    const int ksp = blockIdx.z;
    const int q0 = blockIdx.x * 128 + wave * 32;

    const int c0 = ksp * 11;
    const int c1 = (c0 + 11 < NT) ? c0 + 11 : NT;

    // Q' fragments, resident whole kernel (32 q-rows)
    bf16x8 qf[2][6];
#pragma unroll
    for (int qj = 0; qj < 2; ++qj)
#pragma unroll
        for (int cs = 0; cs < 6; ++cs)
            qf[qj][cs] = *(const bf16x8*)(Qa + ((size_t)h * 2048 + q0 + qj*16 + l15) * CAUG + cs*32 + l4*8);

    f32x4 oacc[4][2];
#pragma unroll
    for (int di = 0; di < 4; ++di)
#pragma unroll
        for (int qj = 0; qj < 2; ++qj) oacc[di][qj] = (f32x4){0.f,0.f,0.f,0.f};
    float mreg[2] = {-1e30f, -1e30f}, lreg[2] = {0.f, 0.f};

    int kr[6], kcb[6], vr[2], vcb[2];
#pragma unroll
    for (int it = 0; it < 6; ++it) { int f = tid*16 + it*4096; kr[it] = f/384; kcb[it] = f%384; }
#pragma unroll
    for (int it = 0; it < 2; ++it) { int f = tid*16 + it*4096; vr[it] = f/128; vcb[it] = f%128; }

    const char* Kg = (const char*)(Ka + (size_t)h * 2048 * CAUG);
    const char* Vg = (const char*)(vt + (size_t)h * 64 * 2048);

    int4v kpre[6], vpre[2];
#pragma unroll
    for (int it = 0; it < 6; ++it) kpre[it] = *(const int4v*)(Kg + (size_t)c0*24576 + (size_t)kr[it]*384 + kcb[it]);
#pragma unroll
    for (int it = 0; it < 2; ++it) vpre[it] = *(const int4v*)(Vg + (size_t)vr[it]*4096 + c0*128 + vcb[it]);

    for (int kt = c0; kt < c1; ++kt) {
        __syncthreads();
#pragma unroll
        for (int it = 0; it < 6; ++it)
            *(int4v*)((char*)&Ks[0][0] + kr[it]*400 + kcb[it]) = kpre[it];
#pragma unroll
        for (int it = 0; it < 2; ++it)
            *(int4v*)((char*)&Vt[0][0] + vr[it]*144 + vcb[it]) = vpre[it];
        __syncthreads();
        if (kt + 1 < c1) {
            const size_t ko = (size_t)(kt + 1) * 24576;
            const size_t vo = (size_t)(kt + 1) * 128;
#pragma unroll
            for (int it = 0; it < 6; ++it) kpre[it] = *(const int4v*)(Kg + ko + (size_t)kr[it]*384 + kcb[it]);
#pragma unroll
            for (int it = 0; it < 2; ++it) vpre[it] = *(const int4v*)(Vg + (size_t)vr[it]*4096 + vo + vcb[it]);
        }

        // ---- scores S^T (64 kpos x 32 q) ----
        f32x4 sacc[4][2];
#pragma unroll
        for (int fi = 0; fi < 4; ++fi)
#pragma unroll
            for (int qj = 0; qj < 2; ++qj) sacc[fi][qj] = (f32x4){0.f,0.f,0.f,0.f};
#pragma unroll
        for (int cs = 0; cs < 6; ++cs) {
            bf16x8 ka[4];
#pragma unroll
            for (int fi = 0; fi < 4; ++fi)
                ka[fi] = *(const bf16x8*)((const char*)&Ks[0][0] + (fi*16 + l15)*400 + cs*64 + l4*16);
#pragma unroll
            for (int fi = 0; fi < 4; ++fi)
#pragma unroll
                for (int qj = 0; qj < 2; ++qj)
                    sacc[fi][qj] = MFMA(ka[fi], qf[qj][cs], sacc[fi][qj]);
        }
        // mask (kpos = frag row)
#pragma unroll
        for (int fi = 0; fi < 4; ++fi) {
            float4 mk = *(const float4*)&mask[kt*64 + fi*16 + l4*4];
            float mv[4] = {mk.x * -10000.f, mk.y * -10000.f, mk.z * -10000.f, mk.w * -10000.f};
#pragma unroll
            for (int qj = 0; qj < 2; ++qj)
#pragma unroll
                for (int r = 0; r < 4; ++r) sacc[fi][qj][r] += mv[r];
        }
        // ---- online softmax per q-column ----
#pragma unroll
        for (int qj = 0; qj < 2; ++qj) {
            float pm = -1e30f;
#pragma unroll
            for (int fi = 0; fi < 4; ++fi)
#pragma unroll
                for (int r = 0; r < 4; ++r) pm = fmaxf(pm, sacc[fi][qj][r]);
            pm = fmaxf(pm, __shfl_xor(pm, 16));
            pm = fmaxf(pm, __shfl_xor(pm, 32));
            const float mnew = fmaxf(mreg[qj], pm);
            const float sc = __expf(mreg[qj] - mnew);
            mreg[qj] = mnew;
            float ps = 0.f;
#pragma unroll
            for (int fi = 0; fi < 4; ++fi)
#pragma unroll
                for (int r = 0; r < 4; ++r) {
                    float p = __expf(sacc[fi][qj][r] - mnew);
                    sacc[fi][qj][r] = p;
                    ps += p;
                }
            ps += __shfl_xor(ps, 16);
            ps += __shfl_xor(ps, 32);
            lreg[qj] = lreg[qj] * sc + ps;
#pragma unroll
            for (int di = 0; di < 4; ++di)
#pragma unroll
                for (int r = 0; r < 4; ++r) oacc[di][qj][r] *= sc;
#pragma unroll
            for (int fi = 0; fi < 4; ++fi) {
                bf16x4 pk;
#pragma unroll
                for (int r = 0; r < 4; ++r) pk[r] = f2bf(sacc[fi][qj][r]);
                *(bf16x4*)(&Pl[wave][qj*16 + l15][fi*16 + l4*4]) = pk;
            }
        }
        // ---- PV: O^T += V^T . P^T ----
#pragma unroll
        for (int cs2 = 0; cs2 < 2; ++cs2) {
            bf16x8 va[4], pb[2];
#pragma unroll
            for (int di = 0; di < 4; ++di)
                va[di] = *(const bf16x8*)((const char*)&Vt[0][0] + (di*16 + l15)*144 + cs2*64 + l4*16);
#pragma unroll
            for (int qj = 0; qj < 2; ++qj)
                pb[qj] = *(const bf16x8*)((const char*)&Pl[wave][0][0] + (qj*16 + l15)*144 + cs2*64 + l4*16);
#pragma unroll
            for (int di = 0; di < 4; ++di)
#pragma unroll
                for (int qj = 0; qj < 2; ++qj)
                    oacc[di][qj] = MFMA(va[di], pb[qj], oacc[di][qj]);
        }
    }

    // epilogue: f32 partials (no division)
#pragma unroll
    for (int qj = 0; qj < 2; ++qj) {
        const int q = q0 + qj*16 + l15;
        float* orow = Opart + (((size_t)(ksp * NH + h)) * 2048 + q) * 64;
#pragma unroll
        for (int di = 0; di < 4; ++di)
            *(f32x4*)(orow + di*16 + l4*4) = oacc[di][qj];
        if (l4 == 0)
            *(float2*)(mlpart + (((size_t)(ksp * NH + h)) * 2048 + q) * 2)
                = make_float2(mreg[qj], lreg[qj]);
    }
}

// ---------------------------------------------------------------------------
// merge NSPLIT flash partials -> ctx bf16 [s][1024]
// thread = (row = h*2048+q, d); lanes contiguous in d -> coalesced
// ---------------------------------------------------------------------------
__global__ __launch_bounds__(256)
void merge_kernel(const float* __restrict__ Opart, const float* __restrict__ mlpart,
                  short* __restrict__ ctxb)
{
    int gid = blockIdx.x * 256 + threadIdx.x;    // 2,097,152
    int d = gid & 63;
    int row = gid >> 6;            // h*2048 + q
    int q = row & 2047, h = row >> 11;
    float mv[NSPLIT], lv[NSPLIT];
    float m = -1e30f;
#pragma unroll
    for (int s = 0; s < NSPLIT; ++s) {
        float2 t = *(const float2*)(mlpart + (((size_t)(s * NH + h)) * 2048 + q) * 2);
        mv[s] = t.x; lv[s] = t.y;
        m = fmaxf(m, mv[s]);
    }
    float O = 0.f, L = 0.f;
#pragma unroll
    for (int s = 0; s < NSPLIT; ++s) {
        float w = __expf(mv[s] - m);
        O = fmaf(w, Opart[(((size_t)(s * NH + h)) * 2048 + q) * 64 + d], O);
        L = fmaf(w, lv[s], L);
    }
    ctxb[(size_t)q * 1024 + h * 64 + d] = f2bf(O / L);
}

// ---------------------------------------------------------------------------
extern "C" void kernel_launch(void* const* d_in, const int* in_sizes, int n_in,
                              void* d_out, int out_size, void* d_ws, size_t ws_size,
                              hipStream_t stream)
{
    const float* hs    = (const float*)d_in[0];
    const float* mask  = (const float*)d_in[1];
    const float* Wq    = (const float*)d_in[2];
    const float* bq    = (const float*)d_in[3];
    const float* Wk    = (const float*)d_in[4];
    const float* bk    = (const float*)d_in[5];
    const float* Wv    = (const float*)d_in[6];
    const float* bv    = (const float*)d_in[7];
    const float* Wo    = (const float*)d_in[8];
    const float* bo    = (const float*)d_in[9];
    const float* omega = (const float*)d_in[10];
    const float* rffb  = (const float*)d_in[11];
    float* out = (float*)d_out;

    short* wsS = (short*)d_ws;
    short* hsb = wsS;                       // 2,097,152
    short* wqb = hsb + 2097152;             // 1,048,576
    short* wkb = wqb + 1048576;
    short* wvb = wkb + 1048576;
    short* wob = wvb + 1048576;
    short* qb  = wob + 1048576;             // 2,097,152
    short* kb  = qb  + 2097152;
    short* vtb = kb  + 2097152;             // 2,097,152  [h][d][s]
    short* ctxb= vtb + 2097152;             // 2,097,152
    short* QaB = ctxb+ 2097152;             // 6,291,456  [h][s][192]
    short* KaB = QaB + 6291456;
    short* omtb= KaB + 6291456;             // 131,072    [h][m][d]
    float* Opart = (float*)(omtb + 131072); // 6,291,456 f32 = [3][16][2048][64]
    float* mlprt = Opart + 6291456;         // 196,608 f32  = [3][16][2048][2]

    conv_kernel<<<6272, 256, 0, stream>>>(hs, Wq, Wk, Wv, Wo, omega,
                                          hsb, wqb, wkb, wvb, wob, omtb);
    gemm_mfma<<<dim3(8, 16, 3), 256, 0, stream>>>(hsb, wqb, bq, qb, wkb, bk, kb, wvb, bv, vtb,
                                                  0, 0, 1, S_LEN);
    phi2_kernel<<<dim3(32, 16, 2), 256, 0, stream>>>(qb, kb, omtb, rffb, QaB, KaB);
    flash_mfma<<<dim3(16, 16, NSPLIT), 256, 0, stream>>>(QaB, KaB, vtb, mask, Opart, mlprt);
    merge_kernel<<<8192, 256, 0, stream>>>(Opart, mlprt, ctxb);
    gemm_mfma<<<dim3(8, 16, 1), 256, 0, stream>>>(ctxb, wob, bo, out, wob, bo, out, wob, bo, out,
                                                  2, 2, 2, S_LEN);
}

// Round 6
// 127.605 us; speedup vs baseline: 1.5619x; 1.5619x over previous
//
#include <hip/hip_runtime.h>
#include <math.h>

#define S_LEN 2048
#define HID   1024
#define NH    16
#define HD    64
#define NM    128
#define CAUG  192
#define KC2   32            // flash K-chunk
#define NCH   32            // chunks per wave-group (2 groups -> 64 chunks total)

constexpr float ALPHA = 0.9f;

typedef __attribute__((ext_vector_type(8))) short bf16x8;
typedef __attribute__((ext_vector_type(4))) short bf16x4;
typedef __attribute__((ext_vector_type(4))) float f32x4;
typedef __attribute__((ext_vector_type(4))) int   int4v;

#define MFMA(a,b,c) __builtin_amdgcn_mfma_f32_16x16x32_bf16(a,b,c,0,0,0)

static __device__ inline short f2bf(float f) {
    unsigned u = __float_as_uint(f);
    u += 0x7fffu + ((u >> 16) & 1u);      // RNE
    return (short)(u >> 16);
}
static __device__ inline float bf2f(short s) {
    return __uint_as_float(((unsigned)(unsigned short)s) << 16);
}

// ---------------------------------------------------------------------------
// fp32 -> bf16 conversion: hs + 4 weights, float4-wide; tail range does the
// omega [h][d][m] -> om_t bf16 [h][m][d] transpose.
// ---------------------------------------------------------------------------
__global__ __launch_bounds__(256)
void conv_kernel(const float* __restrict__ hs,
                 const float* __restrict__ Wq, const float* __restrict__ Wk,
                 const float* __restrict__ Wv, const float* __restrict__ Wo,
                 const float* __restrict__ omega,
                 short* __restrict__ hsb, short* __restrict__ wqb, short* __restrict__ wkb,
                 short* __restrict__ wvb, short* __restrict__ wob, short* __restrict__ omtb)
{
    int i = blockIdx.x * 256 + threadIdx.x;           // f4-unit index
    if (i >= 1605632) return;
    if (i >= 1572864) {                               // omega transpose tail
        int j = (i - 1572864) * 4;                    // elem index in [h][d][m]
        int h = j >> 13, rem = j & 8191;
        int d = rem >> 7, m = rem & 127;
        float4 v = *(const float4*)(omega + j);       // 4 consecutive m
        short* dst = omtb + ((h * 128 + m) << 6) + d; // [h][m][d]
        dst[0]       = f2bf(v.x);
        dst[64]      = f2bf(v.y);
        dst[128]     = f2bf(v.z);
        dst[192]     = f2bf(v.w);
        return;
    }
    const float* src; short* dst; int off;
    if (i < 524288) { src = hs; dst = hsb; off = i; }
    else {
        int j = i - 524288;
        int r = j >> 18;              // 0..3
        off = j & 262143;
        src = (r == 0) ? Wq : (r == 1) ? Wk : (r == 2) ? Wv : Wo;
        dst = (r == 0) ? wqb : (r == 1) ? wkb : (r == 2) ? wvb : wob;
    }
    float4 v = ((const float4*)src)[off];
    bf16x4 o; o[0] = f2bf(v.x); o[1] = f2bf(v.y); o[2] = f2bf(v.z); o[3] = f2bf(v.w);
    ((bf16x4*)dst)[off] = o;
}

// ---------------------------------------------------------------------------
// bf16 MFMA GEMM: C = A(2048x1024) @ W(1024x1024)^T + bias
// mode 0: C bf16 [m][1024];  mode 1: C bf16 transposed [n][Mrows];  mode 2: C f32
// ---------------------------------------------------------------------------
__global__ __launch_bounds__(256)
void gemm_mfma(const short* __restrict__ A,
               const short* __restrict__ W0, const float* __restrict__ b0, void* C0,
               const short* __restrict__ W1, const float* __restrict__ b1, void* C1,
               const short* __restrict__ W2, const float* __restrict__ b2, void* C2,
               int m0_, int m1_, int m2_, int Mrows)
{
    const short* W; const float* bias; void* C; int mode;
    if (blockIdx.z == 0)      { W = W0; bias = b0; C = C0; mode = m0_; }
    else if (blockIdx.z == 1) { W = W1; bias = b1; C = C1; mode = m1_; }
    else                      { W = W2; bias = b2; C = C2; mode = m2_; }

    __shared__ short As[128][40];
    __shared__ short Bs[128][40];

    const int tid = threadIdx.x;
    const int wave = tid >> 6, lane = tid & 63;
    const int l15 = lane & 15, l4 = lane >> 4;
    const int wm = wave >> 1, wn = wave & 1;
    const int m0 = blockIdx.y * 128, n0 = blockIdx.x * 128;

    const int srow = (tid >> 2);
    const int scol = (tid & 3) * 16;

    f32x4 acc[4][4];
#pragma unroll
    for (int i = 0; i < 4; ++i)
#pragma unroll
        for (int j = 0; j < 4; ++j) acc[i][j] = (f32x4){0.f,0.f,0.f,0.f};

    int4v apre[2], bpre[2];
#pragma unroll
    for (int it = 0; it < 2; ++it) {
        apre[it] = *(const int4v*)((const char*)A + (size_t)(m0 + srow + it*64) * 2048 + scol);
        bpre[it] = *(const int4v*)((const char*)W + (size_t)(n0 + srow + it*64) * 2048 + scol);
    }

    for (int ks = 0; ks < 32; ++ks) {
        __syncthreads();
#pragma unroll
        for (int it = 0; it < 2; ++it) {
            *(int4v*)((char*)&As[0][0] + (srow + it*64) * 80 + scol) = apre[it];
            *(int4v*)((char*)&Bs[0][0] + (srow + it*64) * 80 + scol) = bpre[it];
        }
        __syncthreads();
        if (ks + 1 < 32) {
            const int kb = (ks + 1) * 64;
#pragma unroll
            for (int it = 0; it < 2; ++it) {
                apre[it] = *(const int4v*)((const char*)A + (size_t)(m0 + srow + it*64) * 2048 + kb + scol);
                bpre[it] = *(const int4v*)((const char*)W + (size_t)(n0 + srow + it*64) * 2048 + kb + scol);
            }
        }
        bf16x8 af[4], bf[4];
#pragma unroll
        for (int mi = 0; mi < 4; ++mi)
            af[mi] = *(const bf16x8*)((const char*)&As[0][0] + (wm*64 + mi*16 + l15) * 80 + l4*16);
#pragma unroll
        for (int nj = 0; nj < 4; ++nj)
            bf[nj] = *(const bf16x8*)((const char*)&Bs[0][0] + (wn*64 + nj*16 + l15) * 80 + l4*16);
#pragma unroll
        for (int mi = 0; mi < 4; ++mi)
#pragma unroll
            for (int nj = 0; nj < 4; ++nj)
                acc[mi][nj] = MFMA(af[mi], bf[nj], acc[mi][nj]);
    }

#pragma unroll
    for (int nj = 0; nj < 4; ++nj) {
        const int nglob = n0 + wn*64 + nj*16 + l15;
        const float bn = bias[nglob];
#pragma unroll
        for (int mi = 0; mi < 4; ++mi) {
            const int mbase = m0 + wm*64 + mi*16 + l4*4;
            if (mode == 0) {
#pragma unroll
                for (int r = 0; r < 4; ++r)
                    ((short*)C)[(size_t)(mbase + r) * 1024 + nglob] = f2bf(acc[mi][nj][r] + bn);
            } else if (mode == 1) {
                bf16x4 pk;
#pragma unroll
                for (int r = 0; r < 4; ++r) pk[r] = f2bf(acc[mi][nj][r] + bn);
                *(bf16x4*)((short*)C + (size_t)nglob * Mrows + mbase) = pk;
            } else {
#pragma unroll
                for (int r = 0; r < 4; ++r)
                    ((float*)C)[(size_t)(mbase + r) * 1024 + nglob] = acc[mi][nj][r] + bn;
            }
        }
    }
}

// ---------------------------------------------------------------------------
// phi2 (MFMA): per block = one (src, head, 64 s-rows)
// ---------------------------------------------------------------------------
__global__ __launch_bounds__(256)
void phi2_kernel(const short* __restrict__ qbuf, const short* __restrict__ kbuf,
                 const short* __restrict__ omtb, const float* __restrict__ rffb,
                 short* __restrict__ Qa, short* __restrict__ Ka)
{
    __shared__ short om[128][72];
    __shared__ float bsh[128];

    const int src = blockIdx.z, h = blockIdx.y;
    const int s0 = blockIdx.x * 64;
    const short* X = src ? kbuf : qbuf;
    short* Out     = src ? Ka : Qa;
    const float fq   = src ? 1.0f : (ALPHA * 0.125f);
    const float fphi = src ? 1.0f : ((1.0f - ALPHA) * 0.125f);

    const int tid = threadIdx.x, wave = tid >> 6, lane = tid & 63;
    const int l15 = lane & 15, l4 = lane >> 4;

    {
        const char* gsrc = (const char*)(omtb + ((size_t)h << 13));
#pragma unroll
        for (int it = 0; it < 4; ++it) {
            int f = tid * 16 + it * 4096;
            int row = f >> 7, colb = f & 127;
            *(int4v*)((char*)&om[0][0] + row * 144 + colb) = *(const int4v*)(gsrc + f);
        }
        if (tid < 128) bsh[tid] = rffb[h * 128 + tid];
    }
    __syncthreads();

    const int srow = s0 + wave * 16 + l15;

    bf16x8 xf[2];
#pragma unroll
    for (int cs = 0; cs < 2; ++cs)
        xf[cs] = *(const bf16x8*)(X + (size_t)srow * HID + h * HD + cs * 32 + l4 * 8);

    float ss = 0.f;
#pragma unroll
    for (int cs = 0; cs < 2; ++cs)
#pragma unroll
        for (int j = 0; j < 8; ++j) { float v = bf2f(xf[cs][j]); ss = fmaf(v, v, ss); }
    ss += __shfl_xor(ss, 16);
    ss += __shfl_xor(ss, 32);
    const float inv = 1.0f / (sqrtf(ss) + 1e-6f);

    bf16x8 qn[2];
#pragma unroll
    for (int cs = 0; cs < 2; ++cs) {
        bf16x8 o, w;
#pragma unroll
        for (int j = 0; j < 8; ++j) {
            float v = bf2f(xf[cs][j]);
            o[j] = f2bf(v * inv);
            w[j] = f2bf(v * fq);
        }
        qn[cs] = o;
        *(bf16x8*)(Out + ((size_t)h * S_LEN + srow) * CAUG + cs * 32 + l4 * 8) = w;
    }

    f32x4 pacc[8];
#pragma unroll
    for (int t = 0; t < 8; ++t) pacc[t] = (f32x4){0.f,0.f,0.f,0.f};
#pragma unroll
    for (int t = 0; t < 8; ++t)
#pragma unroll
        for (int cs = 0; cs < 2; ++cs) {
            bf16x8 bf = *(const bf16x8*)((const char*)&om[0][0] + (t*16 + l15) * 144 + cs*64 + l4*16);
            pacc[t] = MFMA(qn[cs], bf, pacc[t]);
        }

    float ph[8][4];
    float ps[4] = {0.f, 0.f, 0.f, 0.f};
#pragma unroll
    for (int t = 0; t < 8; ++t) {
        const float bv = bsh[t * 16 + l15];
#pragma unroll
        for (int r = 0; r < 4; ++r) {
            float p = pacc[t][r] + bv;
            float c = 0.125f * __cosf(p);
            ph[t][r] = c;
            ps[r] = fmaf(c, c, ps[r]);
        }
    }
#pragma unroll
    for (int r = 0; r < 4; ++r) {
        ps[r] += __shfl_xor(ps[r], 1);
        ps[r] += __shfl_xor(ps[r], 2);
        ps[r] += __shfl_xor(ps[r], 4);
        ps[r] += __shfl_xor(ps[r], 8);
    }
    float inv2[4];
#pragma unroll
    for (int r = 0; r < 4; ++r) inv2[r] = fphi / (sqrtf(ps[r]) + 1e-6f);

#pragma unroll
    for (int t = 0; t < 8; ++t)
#pragma unroll
        for (int r = 0; r < 4; ++r)
            Out[((size_t)h * S_LEN + s0 + wave * 16 + l4 * 4 + r) * CAUG + 64 + t * 16 + l15]
                = f2bf(ph[t][r] * inv2[r]);
}

// ---------------------------------------------------------------------------
// MFMA flash attention, static-max softmax (scores bounded -> p = exp(s+mask),
// no online max/rescale; PV is a pure sum).  Wave-group K-split:
//   waves 0,1 (group 0): chunks 0..31;  waves 2,3 (group 1): chunks 32..63
// Each wave owns 32 q (qj=2).  Groups have private Ks/Vt buffers (KC=32).
// Final combine via LDS scratch (reuses Ks).  q-tile 64, grid 32x16 = 512
// blocks = 2 blocks/CU (LDS 46 KB).
// ---------------------------------------------------------------------------
__global__ __launch_bounds__(256, 2)
void flash_mfma(const short* __restrict__ Qa, const short* __restrict__ Ka,
                const short* __restrict__ vt, const float* __restrict__ mask,
                short* __restrict__ ctxb)
{
    __shared__ short Ks[2][32][200];   // per-group K chunk: 32 kpos x (192+8) bf16
    __shared__ short Vt[2][64][40];    // per-group V^T chunk: 64 d x (32+8) bf16
    __shared__ short Pl[4][32][40];    // per-wave P: 32 q x (32+8) bf16

    const int tid = threadIdx.x;
    const int wave = tid >> 6, lane = tid & 63;
    const int l15 = lane & 15, l4 = lane >> 4;
    const int g = wave >> 1, sub = wave & 1;
    const int h = blockIdx.y;
    const int q0 = blockIdx.x * 64 + sub * 32;

    // Q' fragments: 32 q rows per wave
    bf16x8 qf[2][6];
#pragma unroll
    for (int qj = 0; qj < 2; ++qj)
#pragma unroll
        for (int cs = 0; cs < 6; ++cs)
            qf[qj][cs] = *(const bf16x8*)(Qa + ((size_t)h * 2048 + q0 + qj*16 + l15) * CAUG + cs*32 + l4*8);

    f32x4 oacc[4][2];
#pragma unroll
    for (int di = 0; di < 4; ++di)
#pragma unroll
        for (int qj = 0; qj < 2; ++qj) oacc[di][qj] = (f32x4){0.f,0.f,0.f,0.f};
    float lsum[2] = {0.f, 0.f};

    // staging geometry (per group: 128 threads stage the group's buffers)
    const int t = tid & 127;
    int kr[6], kcb[6], vr[2], vcb[2];
#pragma unroll
    for (int it = 0; it < 6; ++it) { int f = t*16 + it*2048; kr[it] = f/384; kcb[it] = f%384; }
#pragma unroll
    for (int it = 0; it < 2; ++it) { int f = t*16 + it*2048; vr[it] = f/64; vcb[it] = f%64; }

    const char* Kg = (const char*)(Ka + (size_t)h * 2048 * CAUG);   // rows 384B
    const char* Vg = (const char*)(vt + (size_t)h * 64 * 2048);     // rows 4096B

    int4v kpre[6], vpre[2];
#pragma unroll
    for (int it = 0; it < 6; ++it)
        kpre[it] = *(const int4v*)(Kg + (size_t)(g*NCH)*12288 + (size_t)kr[it]*384 + kcb[it]);
#pragma unroll
    for (int it = 0; it < 2; ++it)
        vpre[it] = *(const int4v*)(Vg + (size_t)vr[it]*4096 + (size_t)(g*NCH)*64 + vcb[it]);

    for (int i = 0; i < NCH; ++i) {
        const int kt = g * NCH + i;
        __syncthreads();                       // group done reading previous chunk
#pragma unroll
        for (int it = 0; it < 6; ++it)
            *(int4v*)((char*)&Ks[g][0][0] + kr[it]*400 + kcb[it]) = kpre[it];
#pragma unroll
        for (int it = 0; it < 2; ++it)
            *(int4v*)((char*)&Vt[g][0][0] + vr[it]*80 + vcb[it]) = vpre[it];
        __syncthreads();
        if (i + 1 < NCH) {
            const size_t ko = (size_t)(kt + 1) * 12288;
            const size_t vo = (size_t)(kt + 1) * 64;
#pragma unroll
            for (int it = 0; it < 6; ++it)
                kpre[it] = *(const int4v*)(Kg + ko + (size_t)kr[it]*384 + kcb[it]);
#pragma unroll
            for (int it = 0; it < 2; ++it)
                vpre[it] = *(const int4v*)(Vg + (size_t)vr[it]*4096 + vo + vcb[it]);
        }

        // ---- scores S^T (32 kpos x 32 q) ----
        f32x4 sacc[2][2];
#pragma unroll
        for (int fi = 0; fi < 2; ++fi)
#pragma unroll
            for (int qj = 0; qj < 2; ++qj) sacc[fi][qj] = (f32x4){0.f,0.f,0.f,0.f};
#pragma unroll
        for (int cs = 0; cs < 6; ++cs) {
            bf16x8 ka[2];
#pragma unroll
            for (int fi = 0; fi < 2; ++fi)
                ka[fi] = *(const bf16x8*)((const char*)&Ks[g][0][0] + (fi*16 + l15)*400 + cs*64 + l4*16);
#pragma unroll
            for (int fi = 0; fi < 2; ++fi)
#pragma unroll
                for (int qj = 0; qj < 2; ++qj)
                    sacc[fi][qj] = MFMA(ka[fi], qf[qj][cs], sacc[fi][qj]);
        }
        // ---- static-max softmax: p = exp(s + mask); accumulate l ----
#pragma unroll
        for (int fi = 0; fi < 2; ++fi) {
            float4 mk = *(const float4*)&mask[kt*32 + fi*16 + l4*4];
            float mv[4] = {mk.x * -10000.f, mk.y * -10000.f, mk.z * -10000.f, mk.w * -10000.f};
#pragma unroll
            for (int qj = 0; qj < 2; ++qj) {
                bf16x4 pk;
#pragma unroll
                for (int r = 0; r < 4; ++r) {
                    float p = __expf(sacc[fi][qj][r] + mv[r]);
                    lsum[qj] += p;
                    pk[r] = f2bf(p);
                }
                *(bf16x4*)((char*)&Pl[wave][0][0] + (qj*16 + l15)*80 + fi*32 + l4*8) = pk;
            }
        }
        // ---- PV: O^T += V^T . P^T ----
        {
            bf16x8 va[4], pb[2];
#pragma unroll
            for (int di = 0; di < 4; ++di)
                va[di] = *(const bf16x8*)((const char*)&Vt[g][0][0] + (di*16 + l15)*80 + l4*16);
#pragma unroll
            for (int qj = 0; qj < 2; ++qj)
                pb[qj] = *(const bf16x8*)((const char*)&Pl[wave][0][0] + (qj*16 + l15)*80 + l4*16);
#pragma unroll
            for (int di = 0; di < 4; ++di)
#pragma unroll
                for (int qj = 0; qj < 2; ++qj)
                    oacc[di][qj] = MFMA(va[di], pb[qj], oacc[di][qj]);
        }
    }

    // reduce l across the 4 kpos lane-groups
#pragma unroll
    for (int qj = 0; qj < 2; ++qj) {
        lsum[qj] += __shfl_xor(lsum[qj], 16);
        lsum[qj] += __shfl_xor(lsum[qj], 32);
    }

    // ---- combine the two K-groups via LDS scratch (reuse Ks/Vt) ----
    __syncthreads();
    float* scrO = (float*)&Ks[0][0][0];    // [2][32][68] f32 = 17408 B
    float* scrL = (float*)&Vt[0][0][0];    // [2][32] f32
    if (g == 1) {
#pragma unroll
        for (int qj = 0; qj < 2; ++qj) {
#pragma unroll
            for (int di = 0; di < 4; ++di)
                *(f32x4*)&scrO[(size_t)(sub*32 + qj*16 + l15)*68 + di*16 + l4*4] = oacc[di][qj];
            if (l4 == 0) scrL[sub*32 + qj*16 + l15] = lsum[qj];
        }
    }
    __syncthreads();
    if (g == 0) {
#pragma unroll
        for (int qj = 0; qj < 2; ++qj) {
            const float l = lsum[qj] + scrL[sub*32 + qj*16 + l15];
            const float inv = 1.0f / l;
            const int s = q0 + qj*16 + l15;
#pragma unroll
            for (int di = 0; di < 4; ++di) {
                f32x4 o2 = *(const f32x4*)&scrO[(size_t)(sub*32 + qj*16 + l15)*68 + di*16 + l4*4];
                bf16x4 ob;
#pragma unroll
                for (int r = 0; r < 4; ++r) ob[r] = f2bf((oacc[di][qj][r] + o2[r]) * inv);
                *(bf16x4*)(ctxb + (size_t)s * HID + h*64 + di*16 + l4*4) = ob;
            }
        }
    }
}

// ---------------------------------------------------------------------------
extern "C" void kernel_launch(void* const* d_in, const int* in_sizes, int n_in,
                              void* d_out, int out_size, void* d_ws, size_t ws_size,
                              hipStream_t stream)
{
    const float* hs    = (const float*)d_in[0];
    const float* mask  = (const float*)d_in[1];
    const float* Wq    = (const float*)d_in[2];
    const float* bq    = (const float*)d_in[3];
    const float* Wk    = (const float*)d_in[4];
    const float* bk    = (const float*)d_in[5];
    const float* Wv    = (const float*)d_in[6];
    const float* bv    = (const float*)d_in[7];
    const float* Wo    = (const float*)d_in[8];
    const float* bo    = (const float*)d_in[9];
    const float* omega = (const float*)d_in[10];
    const float* rffb  = (const float*)d_in[11];
    float* out = (float*)d_out;

    short* wsS = (short*)d_ws;
    short* hsb = wsS;                       // 2,097,152
    short* wqb = hsb + 2097152;             // 1,048,576
    short* wkb = wqb + 1048576;
    short* wvb = wkb + 1048576;
    short* wob = wvb + 1048576;
    short* qb  = wob + 1048576;             // 2,097,152
    short* kb  = qb  + 2097152;
    short* vtb = kb  + 2097152;             // 2,097,152  [h][d][s]
    short* ctxb= vtb + 2097152;             // 2,097,152
    short* QaB = ctxb+ 2097152;             // 6,291,456  [h][s][192]
    short* KaB = QaB + 6291456;
    short* omtb= KaB + 6291456;             // 131,072    [h][m][d]

    conv_kernel<<<6272, 256, 0, stream>>>(hs, Wq, Wk, Wv, Wo, omega,
                                          hsb, wqb, wkb, wvb, wob, omtb);
    gemm_mfma<<<dim3(8, 16, 3), 256, 0, stream>>>(hsb, wqb, bq, qb, wkb, bk, kb, wvb, bv, vtb,
                                                  0, 0, 1, S_LEN);
    phi2_kernel<<<dim3(32, 16, 2), 256, 0, stream>>>(qb, kb, omtb, rffb, QaB, KaB);
    flash_mfma<<<dim3(32, 16), 256, 0, stream>>>(QaB, KaB, vtb, mask, ctxb);
    gemm_mfma<<<dim3(8, 16, 1), 256, 0, stream>>>(ctxb, wob, bo, out, wob, bo, out, wob, bo, out,
                                                  2, 2, 2, S_LEN);
}